// Round 6
// baseline (149.475 us; speedup 1.0000x reference)
//
#include <hip/hip_runtime.h>
#include <hip/hip_bf16.h>

// Shapes (fixed by reference): b=2, h=8, t=8192, dh=128
#define T_SEQ   8192
#define DH      128
#define NBH     16
#define NBUCK   128
#define BSZ     64
#define EPSF    1e-6f

// 16B-granular XOR swizzle (keeps b128 reads contiguous)
#define SWZ(r) (((((r) & 7) ^ (((r) >> 3) & 7))) << 3)

typedef __attribute__((ext_vector_type(8))) __bf16 bf16x8;
typedef __attribute__((ext_vector_type(4))) float  f32x4;

static __device__ __forceinline__ unsigned short f2bf(float f) {
  __bf16 h = (__bf16)f;
  return __builtin_bit_cast(unsigned short, h);
}

// ---------------------------------------------------------------------------
// Kernel 1: bucket sums. grid (128, 16, 2[q|k]), 256 threads. Pure streaming.
// ---------------------------------------------------------------------------
__global__ __launch_bounds__(256) void k_bsum(
    const float* __restrict__ q, const float* __restrict__ k,
    float* __restrict__ x) {
  const int u = blockIdx.x, bh = blockIdx.y, which = blockIdx.z;
  const int t = threadIdx.x;
  const int c4g = t & 31;
  const int r0  = (t >> 5) << 3;
  const float* src = which ? k : q;
  const float* p = src + ((size_t)bh * T_SEQ + (size_t)u * BSZ + r0) * DH + c4g * 4;
  float4 acc = {0.f, 0.f, 0.f, 0.f};
  #pragma unroll
  for (int r = 0; r < 8; r++) {
    float4 vv = *(const float4*)(p + (size_t)r * DH);
    acc.x += vv.x; acc.y += vv.y; acc.z += vv.z; acc.w += vv.w;
  }
  __shared__ float4 xr[8][32];
  xr[t >> 5][c4g] = acc;
  __syncthreads();
  if (t < 32) {
    float4 s4 = xr[0][t];
    #pragma unroll
    for (int j = 1; j < 8; j++) {
      float4 o = xr[j][t];
      s4.x += o.x; s4.y += o.y; s4.z += o.z; s4.w += o.w;
    }
    *(float4*)(x + ((size_t)bh * NBUCK + u) * 256 + which * 128 + t * 4) = s4;
  }
}

// ---------------------------------------------------------------------------
// Kernel 2: sortnet GEMM + relu + gumbel-log. grid (32, 16), 128 threads.
// ---------------------------------------------------------------------------
__global__ __launch_bounds__(128) void k_sortgemm(
    const float* __restrict__ x, const float* __restrict__ W,
    const float* __restrict__ ug, float* __restrict__ rbuf) {
  const int u0 = blockIdx.x * 4, bh = blockIdx.y;
  const int v = threadIdx.x;
  __shared__ float xs[4][256];
  for (int i = v; i < 1024; i += 128)
    xs[i >> 8][i & 255] = x[((size_t)bh * NBUCK + u0 + (i >> 8)) * 256 + (i & 255)];
  __syncthreads();
  const float* Wp = W + (size_t)(bh & 7) * 256 * NBUCK + v;
  float acc0 = 0.f, acc1 = 0.f, acc2 = 0.f, acc3 = 0.f;
  #pragma unroll 16
  for (int e = 0; e < 256; e++) {
    float we = Wp[(size_t)e * NBUCK];
    acc0 += xs[0][e] * we;
    acc1 += xs[1][e] * we;
    acc2 += xs[2][e] * we;
    acc3 += xs[3][e] * we;
  }
  float accs[4] = {acc0, acc1, acc2, acc3};
  #pragma unroll
  for (int j = 0; j < 4; j++) {
    float R = fmaxf(accs[j], 0.f) + EPSF;
    float gu = ug[((size_t)bh * NBUCK + u0 + j) * NBUCK + v] + EPSF;
    float g = -logf(-logf(gu) + EPSF);
    rbuf[((size_t)bh * NBUCK + u0 + j) * NBUCK + v] = (logf(R) + g) * (1.f / 0.75f);
  }
}

// ---------------------------------------------------------------------------
// Kernel 3: sinkhorn, register-resident. grid 16, 512 threads.
// ---------------------------------------------------------------------------
__global__ __launch_bounds__(512, 1) void k_sinkhorn(
    const float* __restrict__ rbuf, int* __restrict__ idxb, float* __restrict__ sb) {
  const int bh = blockIdx.x;
  const int t  = threadIdx.x;
  const int own = t >> 2;
  const int qq  = t & 3;
  __shared__ float rl[128 * 129];
  __shared__ float ca[128], ra[128];

  const float* rb = rbuf + (size_t)bh * (NBUCK * NBUCK);
  for (int i = t; i < NBUCK * NBUCK; i += 512)
    rl[(i >> 7) * 129 + (i & 127)] = rb[i];
  if (t < 128) ca[t] = 0.f;
  __syncthreads();

  float rowv[32], colv[32];
  #pragma unroll
  for (int i4 = 0; i4 < 8; i4++) {
    float4 vv = *(const float4*)(&rl[own * 129 + qq * 32 + i4 * 4]);
    rowv[i4 * 4 + 0] = vv.x; rowv[i4 * 4 + 1] = vv.y;
    rowv[i4 * 4 + 2] = vv.z; rowv[i4 * 4 + 3] = vv.w;
  }
  #pragma unroll
  for (int i = 0; i < 32; i++) colv[i] = rl[(qq * 32 + i) * 129 + own];

  for (int iter = 0; iter < 7; iter++) {
    {
      float vals[32];
      float m = -1e30f;
      #pragma unroll
      for (int i4 = 0; i4 < 8; i4++) {
        float4 cc = *(const float4*)(&ca[qq * 32 + i4 * 4]);
        vals[i4 * 4 + 0] = rowv[i4 * 4 + 0] + cc.x;
        vals[i4 * 4 + 1] = rowv[i4 * 4 + 1] + cc.y;
        vals[i4 * 4 + 2] = rowv[i4 * 4 + 2] + cc.z;
        vals[i4 * 4 + 3] = rowv[i4 * 4 + 3] + cc.w;
      }
      #pragma unroll
      for (int i = 0; i < 32; i++) m = fmaxf(m, vals[i]);
      m = fmaxf(m, __shfl_xor(m, 1));
      m = fmaxf(m, __shfl_xor(m, 2));
      float s0 = 0.f, s1 = 0.f, s2 = 0.f, s3 = 0.f;
      #pragma unroll
      for (int i = 0; i < 8; i++) {
        s0 += __expf(vals[i * 4 + 0] - m);
        s1 += __expf(vals[i * 4 + 1] - m);
        s2 += __expf(vals[i * 4 + 2] - m);
        s3 += __expf(vals[i * 4 + 3] - m);
      }
      float ss = (s0 + s1) + (s2 + s3);
      ss += __shfl_xor(ss, 1);
      ss += __shfl_xor(ss, 2);
      if (qq == 0) ra[own] = -(m + logf(ss));
    }
    __syncthreads();
    {
      float vals[32];
      float m = -1e30f;
      #pragma unroll
      for (int i4 = 0; i4 < 8; i4++) {
        float4 rr = *(const float4*)(&ra[qq * 32 + i4 * 4]);
        vals[i4 * 4 + 0] = colv[i4 * 4 + 0] + rr.x;
        vals[i4 * 4 + 1] = colv[i4 * 4 + 1] + rr.y;
        vals[i4 * 4 + 2] = colv[i4 * 4 + 2] + rr.z;
        vals[i4 * 4 + 3] = colv[i4 * 4 + 3] + rr.w;
      }
      #pragma unroll
      for (int i = 0; i < 32; i++) m = fmaxf(m, vals[i]);
      m = fmaxf(m, __shfl_xor(m, 1));
      m = fmaxf(m, __shfl_xor(m, 2));
      float s0 = 0.f, s1 = 0.f, s2 = 0.f, s3 = 0.f;
      #pragma unroll
      for (int i = 0; i < 8; i++) {
        s0 += __expf(vals[i * 4 + 0] - m);
        s1 += __expf(vals[i * 4 + 1] - m);
        s2 += __expf(vals[i * 4 + 2] - m);
        s3 += __expf(vals[i * 4 + 3] - m);
      }
      float ss = (s0 + s1) + (s2 + s3);
      ss += __shfl_xor(ss, 1);
      ss += __shfl_xor(ss, 2);
      if (qq == 0) ca[own] = -(m + logf(ss));
    }
    __syncthreads();
  }

  {
    float best = -1e30f; int bi = qq * 32;
    #pragma unroll
    for (int i = 0; i < 32; i++) {
      float val = rowv[i] + ca[qq * 32 + i];
      if (val > best) { best = val; bi = qq * 32 + i; }
    }
    #pragma unroll
    for (int d = 1; d < 4; d <<= 1) {
      float ob = __shfl_xor(best, d);
      int   oi = __shfl_xor(bi, d);
      if (ob > best || (ob == best && oi < bi)) { best = ob; bi = oi; }
    }
    if (qq == 0) {
      idxb[bh * NBUCK + own] = bi;
      sb[bh * NBUCK + own]   = expf(rl[own * 129 + bi] + ra[own] + ca[bi]);
    }
  }
}

// ---------------------------------------------------------------------------
// Kernel 4: per-bucket attention. grid (128,16), 256 threads (4 waves).
// K is NOT staged: B-fragments of K are 32B contiguous global loads (L2/L3
// serve the 4x per-block re-read). LDS (48 KB, 3 blocks/CU):
//   [0,16384)     ushorts: Vt[d][j] full (both buckets), swizzled
//   [16384,24576) ushorts: P[64][128], own-wave rows (no barrier needed)
// Exactly ONE __syncthreads (V staged -> PV).
// ---------------------------------------------------------------------------
__global__ __launch_bounds__(256) void k_attn(
    const float* __restrict__ q, const float* __restrict__ k, const float* __restrict__ v,
    const int* __restrict__ idxb, const float* __restrict__ sb, float* __restrict__ out) {
  const int u  = blockIdx.x;
  const int bh = blockIdx.y;
  const int t  = threadIdx.x;
  const int lane = t & 63;
  const int w  = t >> 6;
  const int l15 = lane & 15;
  const int lgp = lane >> 4;

  __shared__ uint4 smem4[3072];   // 48 KB
  unsigned short* sm = (unsigned short*)smem4;
  #define PB 16384

  const int   vidx = idxb[bh * NBUCK + u];
  const float sval = sb[bh * NBUCK + u];
  const size_t hb = (size_t)bh * (T_SEQ * DH);
  const float* qg = q + hb;
  const float* kg = k + hb;
  const float* vg = v + hb;

  // ---- stage Vt full (j<64 = vidx bucket, j>=64 = u bucket), swizzled ----
  #pragma unroll
  for (int it = 0; it < 16; it++) {
    int i = it * 256 + t;
    int j = i & 127;
    int d0 = (i >> 7) << 2;
    int grow = (j < 64) ? (vidx * BSZ + j) : (u * BSZ + (j - 64));
    float4 val = *(const float4*)(vg + (size_t)grow * DH + d0);
    sm[(((d0 + 0) * 128 + j) ^ SWZ(d0 + 0))] = f2bf(val.x);
    sm[(((d0 + 1) * 128 + j) ^ SWZ(d0 + 1))] = f2bf(val.y);
    sm[(((d0 + 2) * 128 + j) ^ SWZ(d0 + 2))] = f2bf(val.z);
    sm[(((d0 + 3) * 128 + j) ^ SWZ(d0 + 3))] = f2bf(val.w);
  }

  // ---- Q fragments direct global -> reg ----
  bf16x8 aQ[4];
  {
    int qrow = u * BSZ + w * 16 + l15;
    const float* qp = qg + (size_t)qrow * DH + lgp * 8;
    #pragma unroll
    for (int kk = 0; kk < 4; kk++) {
      float4 v0 = *(const float4*)(qp + kk * 32);
      float4 v1 = *(const float4*)(qp + kk * 32 + 4);
      bf16x8 f;
      f[0] = (__bf16)v0.x; f[1] = (__bf16)v0.y; f[2] = (__bf16)v0.z; f[3] = (__bf16)v0.w;
      f[4] = (__bf16)v1.x; f[5] = (__bf16)v1.y; f[6] = (__bf16)v1.z; f[7] = (__bf16)v1.w;
      aQ[kk] = f;
    }
  }

  // ---- S = Q K^T, K fragments straight from global (32B/lane each) ----
  const float* kb0 = kg + (size_t)(vidx * BSZ) * DH;   // S cols 0..63
  const float* kb1 = kg + (size_t)(u    * BSZ) * DH;   // S cols 64..127
  f32x4 accS[8];
  #pragma unroll 2
  for (int n = 0; n < 8; n++) {
    const float* kp = ((n < 4) ? (kb0 + (size_t)(n * 16 + l15) * DH)
                               : (kb1 + (size_t)((n - 4) * 16 + l15) * DH)) + lgp * 8;
    f32x4 acc = {0.f, 0.f, 0.f, 0.f};
    #pragma unroll
    for (int kk = 0; kk < 4; kk++) {
      float4 a = *(const float4*)(kp + kk * 32);
      float4 b = *(const float4*)(kp + kk * 32 + 4);
      bf16x8 f;
      f[0] = (__bf16)a.x; f[1] = (__bf16)a.y; f[2] = (__bf16)a.z; f[3] = (__bf16)a.w;
      f[4] = (__bf16)b.x; f[5] = (__bf16)b.y; f[6] = (__bf16)b.z; f[7] = (__bf16)b.w;
      acc = __builtin_amdgcn_mfma_f32_16x16x32_bf16(aQ[kk], f, acc, 0, 0, 0);
    }
    accS[n] = acc;
  }

  // ---- softmax per row (rows in 16-lane groups; shfl_xor reduce) ----
  float pval[8][4];
  float lsum[4];
  #pragma unroll
  for (int r = 0; r < 4; r++) {
    float mm = -1e30f;
    #pragma unroll
    for (int n = 0; n < 8; n++) {
      float lg2 = accS[n][r] * 0.03125f * (n < 4 ? sval : 1.0f);
      pval[n][r] = lg2;
      mm = fmaxf(mm, lg2);
    }
    mm = fmaxf(mm, __shfl_xor(mm, 1));
    mm = fmaxf(mm, __shfl_xor(mm, 2));
    mm = fmaxf(mm, __shfl_xor(mm, 4));
    mm = fmaxf(mm, __shfl_xor(mm, 8));
    float ss = 0.f;
    #pragma unroll
    for (int n = 0; n < 8; n++) {
      float p = __expf(pval[n][r] - mm);
      ss += p;
      pval[n][r] = p * (n < 4 ? sval : 1.0f);
    }
    ss += __shfl_xor(ss, 1);
    ss += __shfl_xor(ss, 2);
    ss += __shfl_xor(ss, 4);
    ss += __shfl_xor(ss, 8);
    lsum[r] = ss;
  }

  // ---- P write (own-wave rows; within-wave DS ordering, no barrier) ----
  #pragma unroll
  for (int n = 0; n < 8; n++) {
    #pragma unroll
    for (int r = 0; r < 4; r++) {
      int prow = w * 16 + lgp * 4 + r;
      int pcol = n * 16 + l15;
      sm[PB + ((prow * 128 + pcol) ^ SWZ(prow))] = f2bf(pval[n][r]);
    }
  }
  // ---- aP fragments (own-wave rows) ----
  bf16x8 aP[4];
  #pragma unroll
  for (int kk = 0; kk < 4; kk++) {
    int prow = w * 16 + l15;
    int c0 = lgp * 8 + kk * 32;
    aP[kk] = *(const bf16x8*)(sm + PB + ((prow * 128 + c0) ^ SWZ(prow)));
  }

  __syncthreads();   // the ONE barrier: all V writes done before V reads

  float invl[4];
  #pragma unroll
  for (int r = 0; r < 4; r++) invl[r] = 1.0f / lsum[r];

  // ---- O = P V (full 4 k-steps) + store ----
  __builtin_amdgcn_s_setprio(1);
  #pragma unroll
  for (int n = 0; n < 8; n++) {
    f32x4 acc = {0.f, 0.f, 0.f, 0.f};
    #pragma unroll
    for (int kk = 0; kk < 4; kk++) {
      int d = n * 16 + l15;
      int jj0 = lgp * 8 + kk * 32;
      bf16x8 bV = *(const bf16x8*)(sm + ((d * 128 + jj0) ^ SWZ(d)));
      acc = __builtin_amdgcn_mfma_f32_16x16x32_bf16(aP[kk], bV, acc, 0, 0, 0);
    }
    #pragma unroll
    for (int r = 0; r < 4; r++) {
      int i2 = w * 16 + lgp * 4 + r;
      int d = n * 16 + l15;
      out[((size_t)bh * T_SEQ + (size_t)u * BSZ + i2) * DH + d] = acc[r] * invl[r];
    }
  }
  __builtin_amdgcn_s_setprio(0);
}

// ---------------------------------------------------------------------------
extern "C" void kernel_launch(void* const* d_in, const int* in_sizes, int n_in,
                              void* d_out, int out_size, void* d_ws, size_t ws_size,
                              hipStream_t stream) {
  (void)in_sizes; (void)n_in; (void)out_size; (void)ws_size;
  const float* q  = (const float*)d_in[0];
  const float* k  = (const float*)d_in[1];
  const float* v  = (const float*)d_in[2];
  const float* W  = (const float*)d_in[3];
  const float* ug = (const float*)d_in[4];
  float* out = (float*)d_out;

  float* xbuf = (float*)d_ws;                                  // 2 MB
  float* rbuf = xbuf + (size_t)NBH * NBUCK * 256;              // 1 MB
  int*   idxb = (int*)(rbuf + (size_t)NBH * NBUCK * NBUCK);
  float* sb   = (float*)(idxb + NBH * NBUCK);

  k_bsum    <<<dim3(NBUCK, NBH, 2), 256, 0, stream>>>(q, k, xbuf);
  k_sortgemm<<<dim3(32, NBH),       128, 0, stream>>>(xbuf, W, ug, rbuf);
  k_sinkhorn<<<NBH,                 512, 0, stream>>>(rbuf, idxb, sb);
  k_attn    <<<dim3(NBUCK, NBH),    256, 0, stream>>>(q, k, v, idxb, sb, out);
}

// Round 7
// 115.859 us; speedup vs baseline: 1.2901x; 1.2901x over previous
//
#include <hip/hip_runtime.h>
#include <hip/hip_bf16.h>

// Shapes (fixed by reference): b=2, h=8, t=8192, dh=128
#define T_SEQ   8192
#define DH      128
#define NBH     16
#define NBUCK   128
#define BSZ     64
#define EPSF    1e-6f

// K-tile swizzle (16B granular, as R5 — measured fine)
#define SWZ(r)  (((((r) & 7) ^ (((r) >> 3) & 7))) << 3)
// V-tile swizzle: rows are 64 ushorts (128B = full bank cycle); spread d-rows
// over 8 x 16B slots keyed by (d>>2) so stride-4-d writes hit distinct slots.
#define VSWZ(d) ((((d) >> 2) & 7) << 3)
// P-tile swizzle: 4 lgp row-groups (prow stride 4) onto disjoint 32B slots.
#define PSWZ(r) ((((r) >> 2) & 3) << 4)

typedef __attribute__((ext_vector_type(8))) __bf16 bf16x8;
typedef __attribute__((ext_vector_type(4))) float  f32x4;

static __device__ __forceinline__ unsigned short f2bf(float f) {
  __bf16 h = (__bf16)f;
  return __builtin_bit_cast(unsigned short, h);
}

// ---------------------------------------------------------------------------
// Kernel 1: bucket sums. grid (128, 16, 2[q|k]), 256 threads. Pure streaming.
// ---------------------------------------------------------------------------
__global__ __launch_bounds__(256) void k_bsum(
    const float* __restrict__ q, const float* __restrict__ k,
    float* __restrict__ x) {
  const int u = blockIdx.x, bh = blockIdx.y, which = blockIdx.z;
  const int t = threadIdx.x;
  const int c4g = t & 31;
  const int r0  = (t >> 5) << 3;
  const float* src = which ? k : q;
  const float* p = src + ((size_t)bh * T_SEQ + (size_t)u * BSZ + r0) * DH + c4g * 4;
  float4 acc = {0.f, 0.f, 0.f, 0.f};
  #pragma unroll
  for (int r = 0; r < 8; r++) {
    float4 vv = *(const float4*)(p + (size_t)r * DH);
    acc.x += vv.x; acc.y += vv.y; acc.z += vv.z; acc.w += vv.w;
  }
  __shared__ float4 xr[8][32];
  xr[t >> 5][c4g] = acc;
  __syncthreads();
  if (t < 32) {
    float4 s4 = xr[0][t];
    #pragma unroll
    for (int j = 1; j < 8; j++) {
      float4 o = xr[j][t];
      s4.x += o.x; s4.y += o.y; s4.z += o.z; s4.w += o.w;
    }
    *(float4*)(x + ((size_t)bh * NBUCK + u) * 256 + which * 128 + t * 4) = s4;
  }
}

// ---------------------------------------------------------------------------
// Kernel 2: sortnet GEMM + relu + gumbel-log. grid (32, 16), 128 threads.
// ---------------------------------------------------------------------------
__global__ __launch_bounds__(128) void k_sortgemm(
    const float* __restrict__ x, const float* __restrict__ W,
    const float* __restrict__ ug, float* __restrict__ rbuf) {
  const int u0 = blockIdx.x * 4, bh = blockIdx.y;
  const int v = threadIdx.x;
  __shared__ float xs[4][256];
  for (int i = v; i < 1024; i += 128)
    xs[i >> 8][i & 255] = x[((size_t)bh * NBUCK + u0 + (i >> 8)) * 256 + (i & 255)];
  __syncthreads();
  const float* Wp = W + (size_t)(bh & 7) * 256 * NBUCK + v;
  float acc0 = 0.f, acc1 = 0.f, acc2 = 0.f, acc3 = 0.f;
  #pragma unroll 16
  for (int e = 0; e < 256; e++) {
    float we = Wp[(size_t)e * NBUCK];
    acc0 += xs[0][e] * we;
    acc1 += xs[1][e] * we;
    acc2 += xs[2][e] * we;
    acc3 += xs[3][e] * we;
  }
  float accs[4] = {acc0, acc1, acc2, acc3};
  #pragma unroll
  for (int j = 0; j < 4; j++) {
    float R = fmaxf(accs[j], 0.f) + EPSF;
    float gu = ug[((size_t)bh * NBUCK + u0 + j) * NBUCK + v] + EPSF;
    float g = -logf(-logf(gu) + EPSF);
    rbuf[((size_t)bh * NBUCK + u0 + j) * NBUCK + v] = (logf(R) + g) * (1.f / 0.75f);
  }
}

// ---------------------------------------------------------------------------
// Kernel 3: sinkhorn, register-resident. grid 16, 512 threads.
// ---------------------------------------------------------------------------
__global__ __launch_bounds__(512, 1) void k_sinkhorn(
    const float* __restrict__ rbuf, int* __restrict__ idxb, float* __restrict__ sb) {
  const int bh = blockIdx.x;
  const int t  = threadIdx.x;
  const int own = t >> 2;
  const int qq  = t & 3;
  __shared__ float rl[128 * 129];
  __shared__ float ca[128], ra[128];

  const float* rb = rbuf + (size_t)bh * (NBUCK * NBUCK);
  for (int i = t; i < NBUCK * NBUCK; i += 512)
    rl[(i >> 7) * 129 + (i & 127)] = rb[i];
  if (t < 128) ca[t] = 0.f;
  __syncthreads();

  float rowv[32], colv[32];
  #pragma unroll
  for (int i4 = 0; i4 < 8; i4++) {
    float4 vv = *(const float4*)(&rl[own * 129 + qq * 32 + i4 * 4]);
    rowv[i4 * 4 + 0] = vv.x; rowv[i4 * 4 + 1] = vv.y;
    rowv[i4 * 4 + 2] = vv.z; rowv[i4 * 4 + 3] = vv.w;
  }
  #pragma unroll
  for (int i = 0; i < 32; i++) colv[i] = rl[(qq * 32 + i) * 129 + own];

  for (int iter = 0; iter < 7; iter++) {
    {
      float vals[32];
      float m = -1e30f;
      #pragma unroll
      for (int i4 = 0; i4 < 8; i4++) {
        float4 cc = *(const float4*)(&ca[qq * 32 + i4 * 4]);
        vals[i4 * 4 + 0] = rowv[i4 * 4 + 0] + cc.x;
        vals[i4 * 4 + 1] = rowv[i4 * 4 + 1] + cc.y;
        vals[i4 * 4 + 2] = rowv[i4 * 4 + 2] + cc.z;
        vals[i4 * 4 + 3] = rowv[i4 * 4 + 3] + cc.w;
      }
      #pragma unroll
      for (int i = 0; i < 32; i++) m = fmaxf(m, vals[i]);
      m = fmaxf(m, __shfl_xor(m, 1));
      m = fmaxf(m, __shfl_xor(m, 2));
      float s0 = 0.f, s1 = 0.f, s2 = 0.f, s3 = 0.f;
      #pragma unroll
      for (int i = 0; i < 8; i++) {
        s0 += __expf(vals[i * 4 + 0] - m);
        s1 += __expf(vals[i * 4 + 1] - m);
        s2 += __expf(vals[i * 4 + 2] - m);
        s3 += __expf(vals[i * 4 + 3] - m);
      }
      float ss = (s0 + s1) + (s2 + s3);
      ss += __shfl_xor(ss, 1);
      ss += __shfl_xor(ss, 2);
      if (qq == 0) ra[own] = -(m + logf(ss));
    }
    __syncthreads();
    {
      float vals[32];
      float m = -1e30f;
      #pragma unroll
      for (int i4 = 0; i4 < 8; i4++) {
        float4 rr = *(const float4*)(&ra[qq * 32 + i4 * 4]);
        vals[i4 * 4 + 0] = colv[i4 * 4 + 0] + rr.x;
        vals[i4 * 4 + 1] = colv[i4 * 4 + 1] + rr.y;
        vals[i4 * 4 + 2] = colv[i4 * 4 + 2] + rr.z;
        vals[i4 * 4 + 3] = colv[i4 * 4 + 3] + rr.w;
      }
      #pragma unroll
      for (int i = 0; i < 32; i++) m = fmaxf(m, vals[i]);
      m = fmaxf(m, __shfl_xor(m, 1));
      m = fmaxf(m, __shfl_xor(m, 2));
      float s0 = 0.f, s1 = 0.f, s2 = 0.f, s3 = 0.f;
      #pragma unroll
      for (int i = 0; i < 8; i++) {
        s0 += __expf(vals[i * 4 + 0] - m);
        s1 += __expf(vals[i * 4 + 1] - m);
        s2 += __expf(vals[i * 4 + 2] - m);
        s3 += __expf(vals[i * 4 + 3] - m);
      }
      float ss = (s0 + s1) + (s2 + s3);
      ss += __shfl_xor(ss, 1);
      ss += __shfl_xor(ss, 2);
      if (qq == 0) ca[own] = -(m + logf(ss));
    }
    __syncthreads();
  }

  {
    float best = -1e30f; int bi = qq * 32;
    #pragma unroll
    for (int i = 0; i < 32; i++) {
      float val = rowv[i] + ca[qq * 32 + i];
      if (val > best) { best = val; bi = qq * 32 + i; }
    }
    #pragma unroll
    for (int d = 1; d < 4; d <<= 1) {
      float ob = __shfl_xor(best, d);
      int   oi = __shfl_xor(bi, d);
      if (ob > best || (ob == best && oi < bi)) { best = ob; bi = oi; }
    }
    if (qq == 0) {
      idxb[bh * NBUCK + own] = bi;
      sb[bh * NBUCK + own]   = expf(rl[own * 129 + bi] + ra[own] + ca[bi]);
    }
  }
}

// ---------------------------------------------------------------------------
// Kernel 4: per-bucket attention. grid (128,16), 256 threads (4 waves).
// 48 KB LDS, 3 barriers. Region map (ushort indices):
//   [0,16384)     K tile [128][128], SWZ      -- dead after B2
//   [16384,24576) V1 half Vt[128d][64j], VSWZ -- staged pre-B1 (dedicated)
//   [0,8192)      P [64][128], PSWZ           -- after B2 (own-wave rows)
//   [8192,16384)  V2 half Vt[128d][64j], VSWZ -- after B2 (K upper half dead)
// V2 loads issued right after B2 (T14 issue-early/write-late, bf16-packed).
// ---------------------------------------------------------------------------
__global__ __launch_bounds__(256) void k_attn(
    const float* __restrict__ q, const float* __restrict__ k, const float* __restrict__ v,
    const int* __restrict__ idxb, const float* __restrict__ sb, float* __restrict__ out) {
  const int u  = blockIdx.x;
  const int bh = blockIdx.y;
  const int t  = threadIdx.x;
  const int lane = t & 63;
  const int w  = t >> 6;
  const int l15 = lane & 15;
  const int lgp = lane >> 4;

  __shared__ uint4 smem4[3072];   // 48 KB
  unsigned short* sm = (unsigned short*)smem4;
  #define VB1 16384
  #define VB2 8192

  const int   vidx = idxb[bh * NBUCK + u];
  const float sval = sb[bh * NBUCK + u];
  const size_t hb = (size_t)bh * (T_SEQ * DH);
  const float* qg = q + hb;
  const float* kg = k + hb;
  const float* vg = v + hb;

  // ---- K -> LDS [0,16384) ----
  #pragma unroll
  for (int it = 0; it < 16; it++) {
    int i = it * 256 + t;
    int row = i >> 5;
    int c4 = (i & 31) << 2;
    int grow = (row < 64) ? (vidx * BSZ + row) : (u * BSZ + (row - 64));
    float4 val = *(const float4*)(kg + (size_t)grow * DH + c4);
    ushort4 hh;
    hh.x = f2bf(val.x); hh.y = f2bf(val.y); hh.z = f2bf(val.z); hh.w = f2bf(val.w);
    *(ushort4*)(sm + (((row * 128 + c4) ^ SWZ(row)))) = hh;
  }
  // ---- V1 (vidx bucket) -> LDS [16384,24576), transposed+VSWZ ----
  #pragma unroll
  for (int it = 0; it < 8; it++) {
    int i = it * 256 + t;
    int d0 = (i & 31) << 2;
    int j  = i >> 5;
    float4 val = *(const float4*)(vg + (size_t)(vidx * BSZ + j) * DH + d0);
    sm[VB1 + (((d0 + 0) * 64 + j) ^ VSWZ(d0 + 0))] = f2bf(val.x);
    sm[VB1 + (((d0 + 1) * 64 + j) ^ VSWZ(d0 + 1))] = f2bf(val.y);
    sm[VB1 + (((d0 + 2) * 64 + j) ^ VSWZ(d0 + 2))] = f2bf(val.z);
    sm[VB1 + (((d0 + 3) * 64 + j) ^ VSWZ(d0 + 3))] = f2bf(val.w);
  }
  // ---- Q fragments direct global -> reg ----
  bf16x8 aQ[4];
  {
    int qrow = u * BSZ + w * 16 + l15;
    const float* qp = qg + (size_t)qrow * DH + lgp * 8;
    #pragma unroll
    for (int kk = 0; kk < 4; kk++) {
      float4 v0 = *(const float4*)(qp + kk * 32);
      float4 v1 = *(const float4*)(qp + kk * 32 + 4);
      bf16x8 f;
      f[0] = (__bf16)v0.x; f[1] = (__bf16)v0.y; f[2] = (__bf16)v0.z; f[3] = (__bf16)v0.w;
      f[4] = (__bf16)v1.x; f[5] = (__bf16)v1.y; f[6] = (__bf16)v1.z; f[7] = (__bf16)v1.w;
      aQ[kk] = f;
    }
  }
  __syncthreads();   // B1: K + V1 staged

  // ---- S = Q K^T ----
  f32x4 accS[8];
  __builtin_amdgcn_s_setprio(1);
  #pragma unroll
  for (int n = 0; n < 8; n++) {
    f32x4 acc = {0.f, 0.f, 0.f, 0.f};
    #pragma unroll
    for (int kk = 0; kk < 4; kk++) {
      int row = n * 16 + l15;
      int c0 = lgp * 8 + kk * 32;
      bf16x8 bK = *(const bf16x8*)(sm + ((row * 128 + c0) ^ SWZ(row)));
      acc = __builtin_amdgcn_mfma_f32_16x16x32_bf16(aQ[kk], bK, acc, 0, 0, 0);
    }
    accS[n] = acc;
  }
  __builtin_amdgcn_s_setprio(0);

  // ---- softmax per row ----
  float pval[8][4];
  float lsum[4];
  #pragma unroll
  for (int r = 0; r < 4; r++) {
    float mm = -1e30f;
    #pragma unroll
    for (int n = 0; n < 8; n++) {
      float lg2 = accS[n][r] * 0.03125f * (n < 4 ? sval : 1.0f);
      pval[n][r] = lg2;
      mm = fmaxf(mm, lg2);
    }
    mm = fmaxf(mm, __shfl_xor(mm, 1));
    mm = fmaxf(mm, __shfl_xor(mm, 2));
    mm = fmaxf(mm, __shfl_xor(mm, 4));
    mm = fmaxf(mm, __shfl_xor(mm, 8));
    float ss = 0.f;
    #pragma unroll
    for (int n = 0; n < 8; n++) {
      float p = __expf(pval[n][r] - mm);
      ss += p;
      pval[n][r] = p * (n < 4 ? sval : 1.0f);
    }
    ss += __shfl_xor(ss, 1);
    ss += __shfl_xor(ss, 2);
    ss += __shfl_xor(ss, 4);
    ss += __shfl_xor(ss, 8);
    lsum[r] = ss;
  }

  __syncthreads();   // B2: K dead; [0,16384) reusable

  // ---- issue V2 loads, convert to bf16 immediately (16 VGPR held) ----
  ushort4 v2s[8];
  #pragma unroll
  for (int it = 0; it < 8; it++) {
    int i = it * 256 + t;
    int d0 = (i & 31) << 2;
    int j  = i >> 5;
    float4 val = *(const float4*)(vg + (size_t)(u * BSZ + j) * DH + d0);
    v2s[it].x = f2bf(val.x); v2s[it].y = f2bf(val.y);
    v2s[it].z = f2bf(val.z); v2s[it].w = f2bf(val.w);
  }

  // ---- write P (own wave rows) into [0,8192), PSWZ ----
  #pragma unroll
  for (int n = 0; n < 8; n++) {
    #pragma unroll
    for (int r = 0; r < 4; r++) {
      int prow = w * 16 + lgp * 4 + r;
      int pcol = n * 16 + l15;
      sm[(prow * 128 + pcol) ^ PSWZ(prow)] = f2bf(pval[n][r]);
    }
  }
  // ---- aP fragments (own-wave rows; in-wave DS ordering, no barrier) ----
  bf16x8 aP[4];
  #pragma unroll
  for (int kk = 0; kk < 4; kk++) {
    int prow = w * 16 + l15;
    int c0 = lgp * 8 + kk * 32;
    aP[kk] = *(const bf16x8*)(sm + ((prow * 128 + c0) ^ PSWZ(prow)));
  }

  // ---- PV part 1 (j = 0..63, V1 region ready since B1) ----
  f32x4 accO[8];
  __builtin_amdgcn_s_setprio(1);
  #pragma unroll
  for (int n = 0; n < 8; n++) {
    f32x4 acc = {0.f, 0.f, 0.f, 0.f};
    #pragma unroll
    for (int kk = 0; kk < 2; kk++) {
      int d = n * 16 + l15;
      int jj0 = lgp * 8 + kk * 32;
      bf16x8 bV = *(const bf16x8*)(sm + VB1 + ((d * 64 + jj0) ^ VSWZ(d)));
      acc = __builtin_amdgcn_mfma_f32_16x16x32_bf16(aP[kk], bV, acc, 0, 0, 0);
    }
    accO[n] = acc;
  }
  __builtin_amdgcn_s_setprio(0);

  // ---- V2 regs -> LDS [8192,16384) ----
  #pragma unroll
  for (int it = 0; it < 8; it++) {
    int i = it * 256 + t;
    int d0 = (i & 31) << 2;
    int j  = i >> 5;
    sm[VB2 + (((d0 + 0) * 64 + j) ^ VSWZ(d0 + 0))] = v2s[it].x;
    sm[VB2 + (((d0 + 1) * 64 + j) ^ VSWZ(d0 + 1))] = v2s[it].y;
    sm[VB2 + (((d0 + 2) * 64 + j) ^ VSWZ(d0 + 2))] = v2s[it].z;
    sm[VB2 + (((d0 + 3) * 64 + j) ^ VSWZ(d0 + 3))] = v2s[it].w;
  }
  __syncthreads();   // B3: V2 ready

  float invl[4];
  #pragma unroll
  for (int r = 0; r < 4; r++) invl[r] = 1.0f / lsum[r];

  // ---- PV part 2 (j = 64..127) + store ----
  __builtin_amdgcn_s_setprio(1);
  #pragma unroll
  for (int n = 0; n < 8; n++) {
    f32x4 acc = accO[n];
    #pragma unroll
    for (int kk = 2; kk < 4; kk++) {
      int d = n * 16 + l15;
      int jj0 = lgp * 8 + (kk - 2) * 32;
      bf16x8 bV = *(const bf16x8*)(sm + VB2 + ((d * 64 + jj0) ^ VSWZ(d)));
      acc = __builtin_amdgcn_mfma_f32_16x16x32_bf16(aP[kk], bV, acc, 0, 0, 0);
    }
    #pragma unroll
    for (int r = 0; r < 4; r++) {
      int i2 = w * 16 + lgp * 4 + r;
      int d = n * 16 + l15;
      out[((size_t)bh * T_SEQ + (size_t)u * BSZ + i2) * DH + d] = acc[r] * invl[r];
    }
  }
  __builtin_amdgcn_s_setprio(0);
}

// ---------------------------------------------------------------------------
extern "C" void kernel_launch(void* const* d_in, const int* in_sizes, int n_in,
                              void* d_out, int out_size, void* d_ws, size_t ws_size,
                              hipStream_t stream) {
  (void)in_sizes; (void)n_in; (void)out_size; (void)ws_size;
  const float* q  = (const float*)d_in[0];
  const float* k  = (const float*)d_in[1];
  const float* v  = (const float*)d_in[2];
  const float* W  = (const float*)d_in[3];
  const float* ug = (const float*)d_in[4];
  float* out = (float*)d_out;

  float* xbuf = (float*)d_ws;                                  // 2 MB
  float* rbuf = xbuf + (size_t)NBH * NBUCK * 256;              // 1 MB
  int*   idxb = (int*)(rbuf + (size_t)NBH * NBUCK * NBUCK);
  float* sb   = (float*)(idxb + NBH * NBUCK);

  k_bsum    <<<dim3(NBUCK, NBH, 2), 256, 0, stream>>>(q, k, xbuf);
  k_sortgemm<<<dim3(32, NBH),       128, 0, stream>>>(xbuf, W, ug, rbuf);
  k_sinkhorn<<<NBH,                 512, 0, stream>>>(rbuf, idxb, sb);
  k_attn    <<<dim3(NBUCK, NBH),    256, 0, stream>>>(q, k, v, idxb, sb, out);
}

// Round 8
// 111.747 us; speedup vs baseline: 1.3376x; 1.0368x over previous
//
#include <hip/hip_runtime.h>
#include <hip/hip_bf16.h>

// Shapes (fixed by reference): b=2, h=8, t=8192, dh=128
#define T_SEQ   8192
#define DH      128
#define NBH     16
#define NBUCK   128
#define BSZ     64
#define EPSF    1e-6f

// K-tile swizzle (16B granular, proven in R5)
#define SWZ(r)  (((((r) & 7) ^ (((r) >> 3) & 7))) << 3)
// V-tile: pitch 72 ushorts (144B -> 4*d bank spread) + (d>>3)-keyed 16B XOR
#define VPITCH 72
#define VXOR(d) ((((d) >> 3) & 7) << 3)
// float4 / ushort4 compile-time component select (folds under full unroll)
#define CF4(v,c) ((c)==0 ? (v).x : (c)==1 ? (v).y : (c)==2 ? (v).z : (v).w)
#define CU4(v,c) ((c)==0 ? (v).x : (c)==1 ? (v).y : (c)==2 ? (v).z : (v).w)

typedef __attribute__((ext_vector_type(8))) __bf16 bf16x8;
typedef __attribute__((ext_vector_type(4))) float  f32x4;

static __device__ __forceinline__ unsigned short f2bf(float f) {
  __bf16 h = (__bf16)f;
  return __builtin_bit_cast(unsigned short, h);
}

// ---------------------------------------------------------------------------
// Kernel 1: bucket sums. grid (128, 16, 2[q|k]), 256 threads. Pure streaming.
// ---------------------------------------------------------------------------
__global__ __launch_bounds__(256) void k_bsum(
    const float* __restrict__ q, const float* __restrict__ k,
    float* __restrict__ x) {
  const int u = blockIdx.x, bh = blockIdx.y, which = blockIdx.z;
  const int t = threadIdx.x;
  const int c4g = t & 31;
  const int r0  = (t >> 5) << 3;
  const float* src = which ? k : q;
  const float* p = src + ((size_t)bh * T_SEQ + (size_t)u * BSZ + r0) * DH + c4g * 4;
  float4 acc = {0.f, 0.f, 0.f, 0.f};
  #pragma unroll
  for (int r = 0; r < 8; r++) {
    float4 vv = *(const float4*)(p + (size_t)r * DH);
    acc.x += vv.x; acc.y += vv.y; acc.z += vv.z; acc.w += vv.w;
  }
  __shared__ float4 xr[8][32];
  xr[t >> 5][c4g] = acc;
  __syncthreads();
  if (t < 32) {
    float4 s4 = xr[0][t];
    #pragma unroll
    for (int j = 1; j < 8; j++) {
      float4 o = xr[j][t];
      s4.x += o.x; s4.y += o.y; s4.z += o.z; s4.w += o.w;
    }
    *(float4*)(x + ((size_t)bh * NBUCK + u) * 256 + which * 128 + t * 4) = s4;
  }
}

// ---------------------------------------------------------------------------
// Kernel 2: sortnet GEMM + relu + gumbel-log. grid (32, 16), 128 threads.
// ---------------------------------------------------------------------------
__global__ __launch_bounds__(128) void k_sortgemm(
    const float* __restrict__ x, const float* __restrict__ W,
    const float* __restrict__ ug, float* __restrict__ rbuf) {
  const int u0 = blockIdx.x * 4, bh = blockIdx.y;
  const int v = threadIdx.x;
  __shared__ float xs[4][256];
  for (int i = v; i < 1024; i += 128)
    xs[i >> 8][i & 255] = x[((size_t)bh * NBUCK + u0 + (i >> 8)) * 256 + (i & 255)];
  __syncthreads();
  const float* Wp = W + (size_t)(bh & 7) * 256 * NBUCK + v;
  float acc0 = 0.f, acc1 = 0.f, acc2 = 0.f, acc3 = 0.f;
  #pragma unroll 16
  for (int e = 0; e < 256; e++) {
    float we = Wp[(size_t)e * NBUCK];
    acc0 += xs[0][e] * we;
    acc1 += xs[1][e] * we;
    acc2 += xs[2][e] * we;
    acc3 += xs[3][e] * we;
  }
  float accs[4] = {acc0, acc1, acc2, acc3};
  #pragma unroll
  for (int j = 0; j < 4; j++) {
    float R = fmaxf(accs[j], 0.f) + EPSF;
    float gu = ug[((size_t)bh * NBUCK + u0 + j) * NBUCK + v] + EPSF;
    float g = -logf(-logf(gu) + EPSF);
    rbuf[((size_t)bh * NBUCK + u0 + j) * NBUCK + v] = (logf(R) + g) * (1.f / 0.75f);
  }
}

// ---------------------------------------------------------------------------
// Kernel 3: sinkhorn, register-resident. grid 16, 512 threads.
// ---------------------------------------------------------------------------
__global__ __launch_bounds__(512, 1) void k_sinkhorn(
    const float* __restrict__ rbuf, int* __restrict__ idxb, float* __restrict__ sb) {
  const int bh = blockIdx.x;
  const int t  = threadIdx.x;
  const int own = t >> 2;
  const int qq  = t & 3;
  __shared__ float rl[128 * 129];
  __shared__ float ca[128], ra[128];

  const float* rb = rbuf + (size_t)bh * (NBUCK * NBUCK);
  for (int i = t; i < NBUCK * NBUCK; i += 512)
    rl[(i >> 7) * 129 + (i & 127)] = rb[i];
  if (t < 128) ca[t] = 0.f;
  __syncthreads();

  float rowv[32], colv[32];
  #pragma unroll
  for (int i4 = 0; i4 < 8; i4++) {
    float4 vv = *(const float4*)(&rl[own * 129 + qq * 32 + i4 * 4]);
    rowv[i4 * 4 + 0] = vv.x; rowv[i4 * 4 + 1] = vv.y;
    rowv[i4 * 4 + 2] = vv.z; rowv[i4 * 4 + 3] = vv.w;
  }
  #pragma unroll
  for (int i = 0; i < 32; i++) colv[i] = rl[(qq * 32 + i) * 129 + own];

  for (int iter = 0; iter < 7; iter++) {
    {
      float vals[32];
      float m = -1e30f;
      #pragma unroll
      for (int i4 = 0; i4 < 8; i4++) {
        float4 cc = *(const float4*)(&ca[qq * 32 + i4 * 4]);
        vals[i4 * 4 + 0] = rowv[i4 * 4 + 0] + cc.x;
        vals[i4 * 4 + 1] = rowv[i4 * 4 + 1] + cc.y;
        vals[i4 * 4 + 2] = rowv[i4 * 4 + 2] + cc.z;
        vals[i4 * 4 + 3] = rowv[i4 * 4 + 3] + cc.w;
      }
      #pragma unroll
      for (int i = 0; i < 32; i++) m = fmaxf(m, vals[i]);
      m = fmaxf(m, __shfl_xor(m, 1));
      m = fmaxf(m, __shfl_xor(m, 2));
      float s0 = 0.f, s1 = 0.f, s2 = 0.f, s3 = 0.f;
      #pragma unroll
      for (int i = 0; i < 8; i++) {
        s0 += __expf(vals[i * 4 + 0] - m);
        s1 += __expf(vals[i * 4 + 1] - m);
        s2 += __expf(vals[i * 4 + 2] - m);
        s3 += __expf(vals[i * 4 + 3] - m);
      }
      float ss = (s0 + s1) + (s2 + s3);
      ss += __shfl_xor(ss, 1);
      ss += __shfl_xor(ss, 2);
      if (qq == 0) ra[own] = -(m + logf(ss));
    }
    __syncthreads();
    {
      float vals[32];
      float m = -1e30f;
      #pragma unroll
      for (int i4 = 0; i4 < 8; i4++) {
        float4 rr = *(const float4*)(&ra[qq * 32 + i4 * 4]);
        vals[i4 * 4 + 0] = colv[i4 * 4 + 0] + rr.x;
        vals[i4 * 4 + 1] = colv[i4 * 4 + 1] + rr.y;
        vals[i4 * 4 + 2] = colv[i4 * 4 + 2] + rr.z;
        vals[i4 * 4 + 3] = colv[i4 * 4 + 3] + rr.w;
      }
      #pragma unroll
      for (int i = 0; i < 32; i++) m = fmaxf(m, vals[i]);
      m = fmaxf(m, __shfl_xor(m, 1));
      m = fmaxf(m, __shfl_xor(m, 2));
      float s0 = 0.f, s1 = 0.f, s2 = 0.f, s3 = 0.f;
      #pragma unroll
      for (int i = 0; i < 8; i++) {
        s0 += __expf(vals[i * 4 + 0] - m);
        s1 += __expf(vals[i * 4 + 1] - m);
        s2 += __expf(vals[i * 4 + 2] - m);
        s3 += __expf(vals[i * 4 + 3] - m);
      }
      float ss = (s0 + s1) + (s2 + s3);
      ss += __shfl_xor(ss, 1);
      ss += __shfl_xor(ss, 2);
      if (qq == 0) ca[own] = -(m + logf(ss));
    }
    __syncthreads();
  }

  {
    float best = -1e30f; int bi = qq * 32;
    #pragma unroll
    for (int i = 0; i < 32; i++) {
      float val = rowv[i] + ca[qq * 32 + i];
      if (val > best) { best = val; bi = qq * 32 + i; }
    }
    #pragma unroll
    for (int d = 1; d < 4; d <<= 1) {
      float ob = __shfl_xor(best, d);
      int   oi = __shfl_xor(bi, d);
      if (ob > best || (ob == best && oi < bi)) { best = ob; bi = oi; }
    }
    if (qq == 0) {
      idxb[bh * NBUCK + own] = bi;
      sb[bh * NBUCK + own]   = expf(rl[own * 129 + bi] + ra[own] + ca[bi]);
    }
  }
}

// ---------------------------------------------------------------------------
// Kernel 4: per-bucket attention. grid (128,16), 256 threads (4 waves).
// R5 structure; LDS 34816B. Region map (ushort indices):
//   [0,16384)     K tile [128][128], SWZ          -- dead after B2
//   [0,8192)      P [64][128], SWZ(prow)          -- after B2 (own-wave rows)
//   [8192,17408)  V half, pitch-72 + VXOR layout  -- V1 after B2, V2 after B4
// V staged via per-thread 4jx8d register micro-transpose: ushort4 writes
// along j -> write <=2-way, b128 reads <=2-way (bank-exact by construction).
// ---------------------------------------------------------------------------
__global__ __launch_bounds__(256) void k_attn(
    const float* __restrict__ q, const float* __restrict__ k, const float* __restrict__ v,
    const int* __restrict__ idxb, const float* __restrict__ sb, float* __restrict__ out) {
  const int u  = blockIdx.x;
  const int bh = blockIdx.y;
  const int t  = threadIdx.x;
  const int lane = t & 63;
  const int w  = t >> 6;
  const int l15 = lane & 15;
  const int lgp = lane >> 4;

  __shared__ uint4 smem4[2176];   // 34816 B = 17408 ushorts
  unsigned short* sm = (unsigned short*)smem4;
  #define VBASE 8192

  const int   vidx = idxb[bh * NBUCK + u];
  const float sval = sb[bh * NBUCK + u];
  const size_t hb = (size_t)bh * (T_SEQ * DH);
  const float* qg = q + hb;
  const float* kg = k + hb;
  const float* vg = v + hb;

  // micro-tile coords for V staging: 4 j-rows x 8 d-cols per thread
  const int vj0 = (t >> 4) * 4;        // 0..60
  const int vd0 = (t & 15) * 8;        // 0..120

  // ---- K -> LDS [0,16384) (interleaved load/cvt/store) ----
  #pragma unroll
  for (int it = 0; it < 16; it++) {
    int i = it * 256 + t;
    int row = i >> 5;
    int c4 = (i & 31) << 2;
    int grow = (row < 64) ? (vidx * BSZ + row) : (u * BSZ + (row - 64));
    float4 val = *(const float4*)(kg + (size_t)grow * DH + c4);
    ushort4 hh;
    hh.x = f2bf(val.x); hh.y = f2bf(val.y); hh.z = f2bf(val.z); hh.w = f2bf(val.w);
    *(ushort4*)(sm + (((row * 128 + c4) ^ SWZ(row)))) = hh;
  }
  // ---- Q fragments direct global -> reg ----
  bf16x8 aQ[4];
  {
    int qrow = u * BSZ + w * 16 + l15;
    const float* qp = qg + (size_t)qrow * DH + lgp * 8;
    #pragma unroll
    for (int kk = 0; kk < 4; kk++) {
      float4 v0 = *(const float4*)(qp + kk * 32);
      float4 v1 = *(const float4*)(qp + kk * 32 + 4);
      bf16x8 f;
      f[0] = (__bf16)v0.x; f[1] = (__bf16)v0.y; f[2] = (__bf16)v0.z; f[3] = (__bf16)v0.w;
      f[4] = (__bf16)v1.x; f[5] = (__bf16)v1.y; f[6] = (__bf16)v1.z; f[7] = (__bf16)v1.w;
      aQ[kk] = f;
    }
  }
  // ---- issue V half-1 loads (4 rows x 8 cols, held in regs until B2) ----
  float4 vpre[4][2];
  #pragma unroll
  for (int r = 0; r < 4; r++) {
    const float* vp = vg + (size_t)(vidx * BSZ + vj0 + r) * DH + vd0;
    vpre[r][0] = *(const float4*)(vp);
    vpre[r][1] = *(const float4*)(vp + 4);
  }
  __syncthreads();   // B1: K staged

  // ---- S = Q K^T ----
  f32x4 accS[8];
  __builtin_amdgcn_s_setprio(1);
  #pragma unroll
  for (int n = 0; n < 8; n++) {
    f32x4 acc = {0.f, 0.f, 0.f, 0.f};
    #pragma unroll
    for (int kk = 0; kk < 4; kk++) {
      int row = n * 16 + l15;
      int c0 = lgp * 8 + kk * 32;
      bf16x8 bK = *(const bf16x8*)(sm + ((row * 128 + c0) ^ SWZ(row)));
      acc = __builtin_amdgcn_mfma_f32_16x16x32_bf16(aQ[kk], bK, acc, 0, 0, 0);
    }
    accS[n] = acc;
  }
  __builtin_amdgcn_s_setprio(0);

  // ---- softmax per row ----
  float pval[8][4];
  float lsum[4];
  #pragma unroll
  for (int r = 0; r < 4; r++) {
    float mm = -1e30f;
    #pragma unroll
    for (int n = 0; n < 8; n++) {
      float lg2 = accS[n][r] * 0.03125f * (n < 4 ? sval : 1.0f);
      pval[n][r] = lg2;
      mm = fmaxf(mm, lg2);
    }
    mm = fmaxf(mm, __shfl_xor(mm, 1));
    mm = fmaxf(mm, __shfl_xor(mm, 2));
    mm = fmaxf(mm, __shfl_xor(mm, 4));
    mm = fmaxf(mm, __shfl_xor(mm, 8));
    float ss = 0.f;
    #pragma unroll
    for (int n = 0; n < 8; n++) {
      float p = __expf(pval[n][r] - mm);
      ss += p;
      pval[n][r] = p * (n < 4 ? sval : 1.0f);
    }
    ss += __shfl_xor(ss, 1);
    ss += __shfl_xor(ss, 2);
    ss += __shfl_xor(ss, 4);
    ss += __shfl_xor(ss, 8);
    lsum[r] = ss;
  }

  __syncthreads();   // B2: K dead; [0,16384) reusable

  // ---- write P (own wave rows) into [0,8192) ----
  #pragma unroll
  for (int n = 0; n < 8; n++) {
    #pragma unroll
    for (int r = 0; r < 4; r++) {
      int prow = w * 16 + lgp * 4 + r;
      int pcol = n * 16 + l15;
      sm[(prow * 128 + pcol) ^ SWZ(prow)] = f2bf(pval[n][r]);
    }
  }
  // ---- V half-1 regs -> LDS (micro-transpose: ushort4 along j) ----
  #pragma unroll
  for (int x = 0; x < 8; x++) {
    int d = vd0 + x;
    int h = x >> 2, c = x & 3;
    ushort4 val;
    val.x = f2bf(CF4(vpre[0][h], c));
    val.y = f2bf(CF4(vpre[1][h], c));
    val.z = f2bf(CF4(vpre[2][h], c));
    val.w = f2bf(CF4(vpre[3][h], c));
    *(ushort4*)(sm + VBASE + d * VPITCH + (vj0 ^ VXOR(d))) = val;
  }
  // ---- issue V half-2 loads (convert+pack immediately; 16 VGPR B2->B4) ----
  ushort4 v2p[4][2];
  #pragma unroll
  for (int r = 0; r < 4; r++) {
    const float* vp = vg + (size_t)(u * BSZ + vj0 + r) * DH + vd0;
    #pragma unroll
    for (int h = 0; h < 2; h++) {
      float4 ld = *(const float4*)(vp + h * 4);
      v2p[r][h].x = f2bf(ld.x); v2p[r][h].y = f2bf(ld.y);
      v2p[r][h].z = f2bf(ld.z); v2p[r][h].w = f2bf(ld.w);
    }
  }
  __syncthreads();   // B3: P + V1 ready

  // ---- aP fragments (own-wave rows) ----
  bf16x8 aP[4];
  #pragma unroll
  for (int kk = 0; kk < 4; kk++) {
    int prow = w * 16 + l15;
    int c0 = lgp * 8 + kk * 32;
    aP[kk] = *(const bf16x8*)(sm + ((prow * 128 + c0) ^ SWZ(prow)));
  }

  // ---- PV part 1 (j = 0..63) ----
  f32x4 accO[8];
  __builtin_amdgcn_s_setprio(1);
  #pragma unroll
  for (int n = 0; n < 8; n++) {
    f32x4 acc = {0.f, 0.f, 0.f, 0.f};
    #pragma unroll
    for (int kk = 0; kk < 2; kk++) {
      int d = n * 16 + l15;
      int jj0 = lgp * 8 + kk * 32;
      bf16x8 bV = *(const bf16x8*)(sm + VBASE + d * VPITCH + (jj0 ^ VXOR(d)));
      acc = __builtin_amdgcn_mfma_f32_16x16x32_bf16(aP[kk], bV, acc, 0, 0, 0);
    }
    accO[n] = acc;
  }
  __builtin_amdgcn_s_setprio(0);
  __syncthreads();   // B4: done reading V1

  // ---- V half-2 regs -> LDS (same micro-transpose) ----
  #pragma unroll
  for (int x = 0; x < 8; x++) {
    int d = vd0 + x;
    int h = x >> 2, c = x & 3;
    ushort4 val;
    val.x = CU4(v2p[0][h], c);
    val.y = CU4(v2p[1][h], c);
    val.z = CU4(v2p[2][h], c);
    val.w = CU4(v2p[3][h], c);
    *(ushort4*)(sm + VBASE + d * VPITCH + (vj0 ^ VXOR(d))) = val;
  }
  __syncthreads();   // B5: V2 ready

  float invl[4];
  #pragma unroll
  for (int r = 0; r < 4; r++) invl[r] = 1.0f / lsum[r];

  // ---- PV part 2 (j = 64..127) + store ----
  __builtin_amdgcn_s_setprio(1);
  #pragma unroll
  for (int n = 0; n < 8; n++) {
    f32x4 acc = accO[n];
    #pragma unroll
    for (int kk = 2; kk < 4; kk++) {
      int d = n * 16 + l15;
      int jj0 = lgp * 8 + (kk - 2) * 32;
      bf16x8 bV = *(const bf16x8*)(sm + VBASE + d * VPITCH + (jj0 ^ VXOR(d)));
      acc = __builtin_amdgcn_mfma_f32_16x16x32_bf16(aP[kk], bV, acc, 0, 0, 0);
    }
    #pragma unroll
    for (int r = 0; r < 4; r++) {
      int i2 = w * 16 + lgp * 4 + r;
      int d = n * 16 + l15;
      out[((size_t)bh * T_SEQ + (size_t)u * BSZ + i2) * DH + d] = acc[r] * invl[r];
    }
  }
  __builtin_amdgcn_s_setprio(0);
}

// ---------------------------------------------------------------------------
extern "C" void kernel_launch(void* const* d_in, const int* in_sizes, int n_in,
                              void* d_out, int out_size, void* d_ws, size_t ws_size,
                              hipStream_t stream) {
  (void)in_sizes; (void)n_in; (void)out_size; (void)ws_size;
  const float* q  = (const float*)d_in[0];
  const float* k  = (const float*)d_in[1];
  const float* v  = (const float*)d_in[2];
  const float* W  = (const float*)d_in[3];
  const float* ug = (const float*)d_in[4];
  float* out = (float*)d_out;

  float* xbuf = (float*)d_ws;                                  // 2 MB
  float* rbuf = xbuf + (size_t)NBH * NBUCK * 256;              // 1 MB
  int*   idxb = (int*)(rbuf + (size_t)NBH * NBUCK * NBUCK);
  float* sb   = (float*)(idxb + NBH * NBUCK);

  k_bsum    <<<dim3(NBUCK, NBH, 2), 256, 0, stream>>>(q, k, xbuf);
  k_sortgemm<<<dim3(32, NBH),       128, 0, stream>>>(xbuf, W, ug, rbuf);
  k_sinkhorn<<<NBH,                 512, 0, stream>>>(rbuf, idxb, sb);
  k_attn    <<<dim3(NBUCK, NBH),    256, 0, stream>>>(q, k, v, idxb, sb, out);
}